// Round 1
// baseline (265.989 us; speedup 1.0000x reference)
//
#include <hip/hip_runtime.h>
#include <hip/hip_bf16.h>
#include <stdint.h>

// Shapes (fixed by the problem)
#define B_  16
#define M_  2048            // T*N
#define C_  256
#define BM_ 32768           // B_*M_

typedef __bf16 bf16x8 __attribute__((ext_vector_type(8)));
typedef float  f32x4  __attribute__((ext_vector_type(4)));

__device__ __forceinline__ unsigned short f2bf(float f) {
    uint32_t u = __builtin_bit_cast(uint32_t, f);
    u += 0x7fffu + ((u >> 16) & 1u);          // RNE
    return (unsigned short)(u >> 16);
}

// ---------------------------------------------------------------- kernel 1
// adjT[d][c] = adj_w[c][d] (bf16); affwB = affine_w (bf16, already [d][c])
__global__ void prep_weights(const float* __restrict__ adj,
                             const float* __restrict__ affw,
                             unsigned short* __restrict__ adjT,
                             unsigned short* __restrict__ affwB) {
    int idx = blockIdx.x * 256 + threadIdx.x;   // 0..65535
    int d = idx >> 8, c = idx & 255;
    adjT[d * 256 + c] = f2bf(adj[c * 256 + d]);
    affwB[idx] = f2bf(affw[idx]);
}

// ---------------------------------------------------------------- kernel 2
// nf = x / max(||x||,1e-12) (bf16), norms = ||x||. One wave per 256-row.
__global__ void l2norm_kernel(const float* __restrict__ x,
                              unsigned short* __restrict__ nf,
                              float* __restrict__ norms) {
    int w = threadIdx.x >> 6, lane = threadIdx.x & 63;
    int row = blockIdx.x * 4 + w;
    const float4 v = *reinterpret_cast<const float4*>(x + (size_t)row * 256 + lane * 4);
    float ss = v.x * v.x + v.y * v.y + v.z * v.z + v.w * v.w;
    #pragma unroll
    for (int m = 1; m < 64; m <<= 1) ss += __shfl_xor(ss, m);
    float nrm = sqrtf(ss);
    float s = 1.0f / fmaxf(nrm, 1e-12f);
    ushort4 o;
    o.x = f2bf(v.x * s); o.y = f2bf(v.y * s); o.z = f2bf(v.z * s); o.w = f2bf(v.w * s);
    *reinterpret_cast<ushort4*>(nf + (size_t)row * 256 + lane * 4) = o;
    if (lane == 0) norms[row] = nrm;
}

// ---------------------------------------------------------------- kernel 3/4
// out[m][n] = alpha_m * sum_k A[m][k]*Bm[n][k] (+ bias[n])
// mode 0: out = Q row-major [BM][256], alpha=1, no bias
// mode 1: out = Vt transposed [256][BM], alpha=norms[m], bias=affine_b
__global__ __launch_bounds__(512, 2)
void gemm_kernel(const unsigned short* __restrict__ A,
                 const unsigned short* __restrict__ Bm,
                 const float* __restrict__ norms,
                 const float* __restrict__ bias,
                 unsigned short* __restrict__ outRM,
                 unsigned short* __restrict__ outT,
                 int mode) {
    __shared__ unsigned short bb[256 * 56];    // [n][32k] padded to 56 (bank-safe)
    int tid = threadIdx.x;
    int w = tid >> 6, lane = tid & 63, g = lane >> 4, r = lane & 15;
    int m0 = blockIdx.x * 128;

    const f32x4 z = {0.f, 0.f, 0.f, 0.f};
    f32x4 acc[16];
    #pragma unroll
    for (int i = 0; i < 16; i++) acc[i] = z;

    for (int dc = 0; dc < 8; dc++) {
        __syncthreads();
        #pragma unroll
        for (int it = 0; it < 2; it++) {       // stage B chunk [256][32]
            int n = (w * 2 + it) * 16 + (lane >> 2);
            int t = lane & 3;
            uint4 val = *reinterpret_cast<const uint4*>(Bm + (size_t)n * 256 + dc * 32 + t * 8);
            *reinterpret_cast<uint4*>(&bb[n * 56 + t * 8]) = val;
        }
        __syncthreads();
        bf16x8 af = *reinterpret_cast<const bf16x8*>(
            A + (size_t)(m0 + w * 16 + r) * 256 + dc * 32 + g * 8);
        #pragma unroll
        for (int nf16 = 0; nf16 < 16; nf16++) {
            bf16x8 bf = *reinterpret_cast<const bf16x8*>(&bb[(nf16 * 16 + r) * 56 + g * 8]);
            acc[nf16] = __builtin_amdgcn_mfma_f32_16x16x32_bf16(af, bf, acc[nf16], 0, 0, 0);
        }
    }
    // D layout: col = lane&15 = n, row = g*4+j = m (within 16)
    if (mode == 0) {
        #pragma unroll
        for (int nf16 = 0; nf16 < 16; nf16++) {
            int n = nf16 * 16 + r;
            #pragma unroll
            for (int j = 0; j < 4; j++) {
                int m = m0 + w * 16 + g * 4 + j;
                outRM[(size_t)m * 256 + n] = f2bf(acc[nf16][j]);
            }
        }
    } else {
        float4 nr = *reinterpret_cast<const float4*>(norms + m0 + w * 16 + g * 4);
        #pragma unroll
        for (int nf16 = 0; nf16 < 16; nf16++) {
            int n = nf16 * 16 + r;
            float bv = bias[n];
            ushort4 o;
            o.x = f2bf(acc[nf16][0] * nr.x + bv);
            o.y = f2bf(acc[nf16][1] * nr.y + bv);
            o.z = f2bf(acc[nf16][2] * nr.z + bv);
            o.w = f2bf(acc[nf16][3] * nr.w + bv);
            *reinterpret_cast<ushort4*>(outT + (size_t)n * BM_ + m0 + w * 16 + g * 4) = o;
        }
    }
}

// ---------------------------------------------------------------- kernel 5
// Flash: per block 64 q-rows (4 waves x 16), loop 32 kv-steps of 64.
// S^T = mfma(K, Q)  -> D col = q (lane&15), row = kv
// out^T = mfma(Vt, P^T) -> D col = q, row = c  => contiguous float4 epilogue
__global__ __launch_bounds__(256, 2)
void flash_kernel(const unsigned short* __restrict__ Q,
                  const unsigned short* __restrict__ K,
                  const unsigned short* __restrict__ Vt,
                  float* __restrict__ out) {
    __shared__ char smem[65536];
    char* kbuf = smem;              // [64 kv][512B] xor-swizzled 16B slots
    char* vbuf = smem + 32768;      // [256 c][128B] xor-swizzled
    int tid = threadIdx.x;
    int w = tid >> 6, lane = tid & 63, g = lane >> 4, r = lane & 15;
    int b = blockIdx.x >> 5;
    int mblk = blockIdx.x & 31;
    int q0 = b * M_ + mblk * 64 + w * 16;     // + r = this lane's q row
    char* ptile = smem + w * 2304;            // wave-private P [16][72 bf16], aliases kbuf front

    bf16x8 qf[8];
    #pragma unroll
    for (int dc = 0; dc < 8; dc++)
        qf[dc] = *reinterpret_cast<const bf16x8*>(Q + (size_t)(q0 + r) * 256 + dc * 32 + g * 8);

    const f32x4 z = {0.f, 0.f, 0.f, 0.f};
    f32x4 acc[16];
    #pragma unroll
    for (int i = 0; i < 16; i++) acc[i] = z;
    float mmax = -1e30f, lsum = 0.0f;

    for (int step = 0; step < 32; step++) {
        int n0 = step * 64;
        uint4 kv_[8], vv_[8];
        #pragma unroll
        for (int it = 0; it < 8; it++) {       // issue K loads before barrier
            int chunk = w * 8 + it;
            int n = chunk * 2 + (lane >> 5);
            int t = lane & 31;
            kv_[it] = *reinterpret_cast<const uint4*>(
                K + (size_t)(b * M_ + n0 + n) * 256 + t * 8);
        }
        __syncthreads();                       // prior-step LDS reads done
        #pragma unroll
        for (int it = 0; it < 8; it++) {       // V loads overlap K ds_writes
            int chunk = w * 8 + it;
            int c = chunk * 8 + (lane >> 3);
            int t = lane & 7;
            vv_[it] = *reinterpret_cast<const uint4*>(
                Vt + (size_t)c * BM_ + (size_t)b * M_ + n0 + t * 8);
        }
        #pragma unroll
        for (int it = 0; it < 8; it++) {
            int chunk = w * 8 + it;
            int n = chunk * 2 + (lane >> 5);
            int t = lane & 31;
            int slot = t ^ (n & 7);
            *reinterpret_cast<uint4*>(kbuf + n * 512 + slot * 16) = kv_[it];
        }
        #pragma unroll
        for (int it = 0; it < 8; it++) {
            int chunk = w * 8 + it;
            int c = chunk * 8 + (lane >> 3);
            int t = lane & 7;
            int slot = t ^ (c & 7);
            *reinterpret_cast<uint4*>(vbuf + c * 128 + slot * 16) = vv_[it];
        }
        __syncthreads();                       // staging visible

        // ---- S^T = K . Q^T
        f32x4 sf[4];
        #pragma unroll
        for (int i = 0; i < 4; i++) sf[i] = z;
        #pragma unroll
        for (int dc = 0; dc < 8; dc++) {
            #pragma unroll
            for (int nb = 0; nb < 4; nb++) {
                int n = nb * 16 + r;
                int slot = (dc * 4 + g) ^ (r & 7);
                bf16x8 kf = *reinterpret_cast<const bf16x8*>(kbuf + n * 512 + slot * 16);
                sf[nb] = __builtin_amdgcn_mfma_f32_16x16x32_bf16(kf, qf[dc], sf[nb], 0, 0, 0);
            }
        }
        __syncthreads();                       // all K reads done before P aliases kbuf

        // ---- online softmax on logits 5*s ; lane state is for q = r
        float tm = -1e30f;
        #pragma unroll
        for (int nb = 0; nb < 4; nb++) {
            tm = fmaxf(tm, fmaxf(fmaxf(sf[nb][0], sf[nb][1]), fmaxf(sf[nb][2], sf[nb][3])));
        }
        tm = fmaxf(tm, __shfl_xor(tm, 16));
        tm = fmaxf(tm, __shfl_xor(tm, 32));
        float Mnew = fmaxf(mmax, 5.0f * tm);
        float corr = __expf(mmax - Mnew);
        mmax = Mnew;
        lsum *= corr;
        #pragma unroll
        for (int i = 0; i < 16; i++) {
            acc[i][0] *= corr; acc[i][1] *= corr; acc[i][2] *= corr; acc[i][3] *= corr;
        }
        float rs = 0.0f;
        #pragma unroll
        for (int nb = 0; nb < 4; nb++) {
            float p0 = __expf(5.0f * sf[nb][0] - mmax);
            float p1 = __expf(5.0f * sf[nb][1] - mmax);
            float p2 = __expf(5.0f * sf[nb][2] - mmax);
            float p3 = __expf(5.0f * sf[nb][3] - mmax);
            rs += (p0 + p1) + (p2 + p3);
            uint32_t u01 = (uint32_t)f2bf(p0) | ((uint32_t)f2bf(p1) << 16);
            uint32_t u23 = (uint32_t)f2bf(p2) | ((uint32_t)f2bf(p3) << 16);
            // P[q=r][kv = nb*16 + g*4 + j], row stride 144B
            *reinterpret_cast<uint32_t*>(ptile + r * 144 + (nb * 16 + g * 4) * 2) = u01;
            *reinterpret_cast<uint32_t*>(ptile + r * 144 + (nb * 16 + g * 4) * 2 + 4) = u23;
        }
        rs += __shfl_xor(rs, 16);
        rs += __shfl_xor(rs, 32);
        lsum += rs;

        // ---- out^T += Vt . P^T
        bf16x8 pb[2];
        #pragma unroll
        for (int ch = 0; ch < 2; ch++)
            pb[ch] = *reinterpret_cast<const bf16x8*>(ptile + r * 144 + ch * 64 + g * 16);
        #pragma unroll
        for (int cf = 0; cf < 16; cf++) {
            #pragma unroll
            for (int ch = 0; ch < 2; ch++) {
                int c = cf * 16 + r;
                int slot = (ch * 4 + g) ^ (r & 7);
                bf16x8 vf = *reinterpret_cast<const bf16x8*>(vbuf + c * 128 + slot * 16);
                acc[cf] = __builtin_amdgcn_mfma_f32_16x16x32_bf16(vf, pb[ch], acc[cf], 0, 0, 0);
            }
        }
    }

    float inv = 1.0f / lsum;
    #pragma unroll
    for (int cf = 0; cf < 16; cf++) {
        float4 o;
        o.x = acc[cf][0] * inv; o.y = acc[cf][1] * inv;
        o.z = acc[cf][2] * inv; o.w = acc[cf][3] * inv;
        *reinterpret_cast<float4*>(out + (size_t)(q0 + r) * 256 + cf * 16 + g * 4) = o;
    }
}

// ---------------------------------------------------------------- kernel 6
// In-place LayerNorm + LeakyReLU over C=256. One wave per row.
__global__ void ln_kernel(float* __restrict__ out,
                          const float* __restrict__ gam,
                          const float* __restrict__ bet) {
    int w = threadIdx.x >> 6, lane = threadIdx.x & 63;
    size_t row = (size_t)blockIdx.x * 4 + w;
    float4 v = *reinterpret_cast<float4*>(out + row * 256 + lane * 4);
    float s = v.x + v.y + v.z + v.w;
    float q = v.x * v.x + v.y * v.y + v.z * v.z + v.w * v.w;
    #pragma unroll
    for (int m = 1; m < 64; m <<= 1) { s += __shfl_xor(s, m); q += __shfl_xor(q, m); }
    float mu = s * (1.0f / 256.0f);
    float var = q * (1.0f / 256.0f) - mu * mu;
    float rstd = rsqrtf(var + 1e-5f);
    float4 gg = *reinterpret_cast<const float4*>(gam + lane * 4);
    float4 bb = *reinterpret_cast<const float4*>(bet + lane * 4);
    float4 o;
    o.x = (v.x - mu) * rstd * gg.x + bb.x;
    o.y = (v.y - mu) * rstd * gg.y + bb.y;
    o.z = (v.z - mu) * rstd * gg.z + bb.z;
    o.w = (v.w - mu) * rstd * gg.w + bb.w;
    o.x = o.x >= 0.f ? o.x : 0.01f * o.x;
    o.y = o.y >= 0.f ? o.y : 0.01f * o.y;
    o.z = o.z >= 0.f ? o.z : 0.01f * o.z;
    o.w = o.w >= 0.f ? o.w : 0.01f * o.w;
    *reinterpret_cast<float4*>(out + row * 256 + lane * 4) = o;
}

// ---------------------------------------------------------------- launcher
extern "C" void kernel_launch(void* const* d_in, const int* in_sizes, int n_in,
                              void* d_out, int out_size, void* d_ws, size_t ws_size,
                              hipStream_t stream) {
    const float* local_feat = (const float*)d_in[0];
    // d_in[1] (global_feat) and d_in[2] (pos) are unused by the reference.
    const float* adj_w    = (const float*)d_in[3];
    const float* affine_w = (const float*)d_in[4];
    const float* affine_b = (const float*)d_in[5];
    const float* ln_g     = (const float*)d_in[6];
    const float* ln_b     = (const float*)d_in[7];
    float* out = (float*)d_out;

    char* ws = (char*)d_ws;
    unsigned short* nf    = (unsigned short*)(ws);                 // 16 MiB  bf16 [BM][256]
    unsigned short* q     = (unsigned short*)(ws + 16777216);      // 16 MiB  bf16 [BM][256]
    unsigned short* vt    = (unsigned short*)(ws + 33554432);      // 16 MiB  bf16 [256][BM]
    float*          norms = (float*)         (ws + 50331648);      // 128 KiB f32  [BM]
    unsigned short* adjT  = (unsigned short*)(ws + 50462720);      // 128 KiB
    unsigned short* affw  = (unsigned short*)(ws + 50593792);      // 128 KiB

    prep_weights<<<256, 256, 0, stream>>>(adj_w, affine_w, adjT, affw);
    l2norm_kernel<<<BM_ / 4, 256, 0, stream>>>(local_feat, nf, norms);
    gemm_kernel<<<BM_ / 128, 512, 0, stream>>>(nf, adjT, nullptr, nullptr, q, nullptr, 0);
    gemm_kernel<<<BM_ / 128, 512, 0, stream>>>(nf, affw, norms, affine_b, nullptr, vt, 1);
    flash_kernel<<<B_ * (M_ / 64), 256, 0, stream>>>(q, nf, vt, out);
    ln_kernel<<<BM_ / 4, 256, 0, stream>>>(out, ln_g, ln_b);
}

// Round 2
// 185.655 us; speedup vs baseline: 1.4327x; 1.4327x over previous
//
#include <hip/hip_runtime.h>
#include <hip/hip_bf16.h>
#include <stdint.h>

// Shapes (fixed by the problem)
#define B_  16
#define M_  2048            // T*N
#define C_  256
#define BM_ 32768           // B_*M_

typedef __bf16 bf16x8 __attribute__((ext_vector_type(8)));
typedef float  f32x4  __attribute__((ext_vector_type(4)));

__device__ __forceinline__ unsigned short f2bf(float f) {
    uint32_t u = __builtin_bit_cast(uint32_t, f);
    u += 0x7fffu + ((u >> 16) & 1u);          // RNE
    return (unsigned short)(u >> 16);
}

// async global->LDS, 16B per lane; LDS dest = wave-uniform base + lane*16
__device__ __forceinline__ void gload16(const void* g, void* l) {
    __builtin_amdgcn_global_load_lds(
        (const __attribute__((address_space(1))) void*)g,
        (__attribute__((address_space(3))) void*)l, 16, 0, 0);
}

// ---------------------------------------------------------------- kernel 1
__global__ void prep_weights(const float* __restrict__ adj,
                             const float* __restrict__ affw,
                             unsigned short* __restrict__ adjT,
                             unsigned short* __restrict__ affwB) {
    int idx = blockIdx.x * 256 + threadIdx.x;   // 0..65535
    int d = idx >> 8, c = idx & 255;
    adjT[d * 256 + c] = f2bf(adj[c * 256 + d]);
    affwB[idx] = f2bf(affw[idx]);
}

// ---------------------------------------------------------------- kernel 2
__global__ void l2norm_kernel(const float* __restrict__ x,
                              unsigned short* __restrict__ nf,
                              float* __restrict__ norms) {
    int w = threadIdx.x >> 6, lane = threadIdx.x & 63;
    int row = blockIdx.x * 4 + w;
    const float4 v = *reinterpret_cast<const float4*>(x + (size_t)row * 256 + lane * 4);
    float ss = v.x * v.x + v.y * v.y + v.z * v.z + v.w * v.w;
    #pragma unroll
    for (int m = 1; m < 64; m <<= 1) ss += __shfl_xor(ss, m);
    float nrm = sqrtf(ss);
    float s = 1.0f / fmaxf(nrm, 1e-12f);
    ushort4 o;
    o.x = f2bf(v.x * s); o.y = f2bf(v.y * s); o.z = f2bf(v.z * s); o.w = f2bf(v.w * s);
    *reinterpret_cast<ushort4*>(nf + (size_t)row * 256 + lane * 4) = o;
    if (lane == 0) norms[row] = nrm;
}

// ---------------------------------------------------------------- kernel 3/4
__global__ __launch_bounds__(512, 2)
void gemm_kernel(const unsigned short* __restrict__ A,
                 const unsigned short* __restrict__ Bm,
                 const float* __restrict__ norms,
                 const float* __restrict__ bias,
                 unsigned short* __restrict__ outRM,
                 unsigned short* __restrict__ outT,
                 int mode) {
    __shared__ unsigned short bb[256 * 56];
    int tid = threadIdx.x;
    int w = tid >> 6, lane = tid & 63, g = lane >> 4, r = lane & 15;
    int m0 = blockIdx.x * 128;

    const f32x4 z = {0.f, 0.f, 0.f, 0.f};
    f32x4 acc[16];
    #pragma unroll
    for (int i = 0; i < 16; i++) acc[i] = z;

    for (int dc = 0; dc < 8; dc++) {
        __syncthreads();
        #pragma unroll
        for (int it = 0; it < 2; it++) {
            int n = (w * 2 + it) * 16 + (lane >> 2);
            int t = lane & 3;
            uint4 val = *reinterpret_cast<const uint4*>(Bm + (size_t)n * 256 + dc * 32 + t * 8);
            *reinterpret_cast<uint4*>(&bb[n * 56 + t * 8]) = val;
        }
        __syncthreads();
        bf16x8 af = *reinterpret_cast<const bf16x8*>(
            A + (size_t)(m0 + w * 16 + r) * 256 + dc * 32 + g * 8);
        #pragma unroll
        for (int nf16 = 0; nf16 < 16; nf16++) {
            bf16x8 bf = *reinterpret_cast<const bf16x8*>(&bb[(nf16 * 16 + r) * 56 + g * 8]);
            acc[nf16] = __builtin_amdgcn_mfma_f32_16x16x32_bf16(af, bf, acc[nf16], 0, 0, 0);
        }
    }
    if (mode == 0) {
        #pragma unroll
        for (int nf16 = 0; nf16 < 16; nf16++) {
            int n = nf16 * 16 + r;
            #pragma unroll
            for (int j = 0; j < 4; j++) {
                int m = m0 + w * 16 + g * 4 + j;
                outRM[(size_t)m * 256 + n] = f2bf(acc[nf16][j]);
            }
        }
    } else {
        float4 nr = *reinterpret_cast<const float4*>(norms + m0 + w * 16 + g * 4);
        #pragma unroll
        for (int nf16 = 0; nf16 < 16; nf16++) {
            int n = nf16 * 16 + r;
            float bv = bias[n];
            ushort4 o;
            o.x = f2bf(acc[nf16][0] * nr.x + bv);
            o.y = f2bf(acc[nf16][1] * nr.y + bv);
            o.z = f2bf(acc[nf16][2] * nr.z + bv);
            o.w = f2bf(acc[nf16][3] * nr.w + bv);
            *reinterpret_cast<ushort4*>(outT + (size_t)n * BM_ + m0 + w * 16 + g * 4) = o;
        }
    }
}

// ---------------------------------------------------------------- kernel 5
// Flash v2: 4 waves x 32 q-rows = 128 q/block, grid 256 (1 block/CU).
// K/V double-buffered via global_load_lds (pre-swizzled global source,
// linear LDS dest, XOR-swizzled reads). P per-wave tile in LDS.
// Epilogue fuses 1/lsum scale + LayerNorm + LeakyReLU.
// LDS: kbuf[2] @0 (2x32KB), vbuf[2] @65536 (2x32KB), ptile @131072 (4x4608)
__global__ __launch_bounds__(256, 1)
void flash_kernel(const unsigned short* __restrict__ Q,
                  const unsigned short* __restrict__ K,
                  const unsigned short* __restrict__ Vt,
                  const float* __restrict__ gam,
                  const float* __restrict__ bet,
                  float* __restrict__ out) {
    __shared__ char smem[149504];
    int tid = threadIdx.x;
    int w = tid >> 6, lane = tid & 63, g = lane >> 4, r = lane & 15;
    // XCD-pinned mapping: xcd = blk&7 owns batches {2*xcd, 2*xcd+1} (4MB = L2)
    int blk = blockIdx.x;
    int b = (blk & 7) * 2 + (blk >> 7);
    int mblk = (blk >> 3) & 15;
    int q0 = b * M_ + mblk * 128 + w * 32;
    char* ptile = smem + 131072 + w * 4608;   // [32 q][144B]

    bf16x8 qf[2][8];
    #pragma unroll
    for (int qh = 0; qh < 2; qh++)
        #pragma unroll
        for (int dc = 0; dc < 8; dc++)
            qf[qh][dc] = *reinterpret_cast<const bf16x8*>(
                Q + (size_t)(q0 + qh * 16 + r) * 256 + dc * 32 + g * 8);

    const f32x4 z = {0.f, 0.f, 0.f, 0.f};
    f32x4 acc[2][16];
    #pragma unroll
    for (int qh = 0; qh < 2; qh++)
        #pragma unroll
        for (int i = 0; i < 16; i++) acc[qh][i] = z;
    float mmax[2] = {-1e30f, -1e30f}, lsum[2] = {0.0f, 0.0f};

    auto stage = [&](int step, int bufsel) {
        int base = b * M_ + step * 64;
        char* kb = smem + bufsel * 32768;
        char* vb = smem + 65536 + bufsel * 32768;
        #pragma unroll
        for (int it = 0; it < 8; it++) {
            int chunk = w * 8 + it;
            int n = chunk * 2 + (lane >> 5);
            int s = lane & 31;
            gload16(K + (size_t)(base + n) * 256 + ((s ^ (n & 7)) * 8),
                    kb + chunk * 1024);
        }
        #pragma unroll
        for (int it = 0; it < 8; it++) {
            int chunk = w * 8 + it;
            int c = chunk * 8 + (lane >> 3);
            int s = lane & 7;
            gload16(Vt + (size_t)c * BM_ + base + ((s ^ (c & 7)) * 8),
                    vb + chunk * 1024);
        }
    };

    stage(0, 0);
    __syncthreads();                            // drains vmcnt + barrier

    for (int step = 0; step < 32; step++) {
        int cur = step & 1;
        if (step + 1 < 32) stage(step + 1, cur ^ 1);  // async over this step's compute
        char* kb = smem + cur * 32768;
        char* vb = smem + 65536 + cur * 32768;

        // ---- S^T = K . Q^T : 32 kf reads -> 64 MFMAs
        f32x4 sf[2][4];
        #pragma unroll
        for (int qh = 0; qh < 2; qh++)
            #pragma unroll
            for (int i = 0; i < 4; i++) sf[qh][i] = z;
        #pragma unroll
        for (int dc = 0; dc < 8; dc++) {
            #pragma unroll
            for (int nb = 0; nb < 4; nb++) {
                int n = nb * 16 + r;
                int slot = (dc * 4 + g) ^ (r & 7);
                bf16x8 kf = *reinterpret_cast<const bf16x8*>(kb + n * 512 + slot * 16);
                sf[0][nb] = __builtin_amdgcn_mfma_f32_16x16x32_bf16(kf, qf[0][dc], sf[0][nb], 0, 0, 0);
                sf[1][nb] = __builtin_amdgcn_mfma_f32_16x16x32_bf16(kf, qf[1][dc], sf[1][nb], 0, 0, 0);
            }
        }

        // ---- online softmax per q-half; lane state is q = qh*16 + r
        #pragma unroll
        for (int qh = 0; qh < 2; qh++) {
            float tm = -1e30f;
            #pragma unroll
            for (int nb = 0; nb < 4; nb++)
                tm = fmaxf(tm, fmaxf(fmaxf(sf[qh][nb][0], sf[qh][nb][1]),
                                     fmaxf(sf[qh][nb][2], sf[qh][nb][3])));
            tm = fmaxf(tm, __shfl_xor(tm, 16));
            tm = fmaxf(tm, __shfl_xor(tm, 32));
            float Mnew = fmaxf(mmax[qh], 5.0f * tm);
            float corr = __expf(mmax[qh] - Mnew);
            mmax[qh] = Mnew;
            lsum[qh] *= corr;
            #pragma unroll
            for (int i = 0; i < 16; i++) {
                acc[qh][i][0] *= corr; acc[qh][i][1] *= corr;
                acc[qh][i][2] *= corr; acc[qh][i][3] *= corr;
            }
            float rs = 0.0f;
            #pragma unroll
            for (int nb = 0; nb < 4; nb++) {
                float p0 = __expf(5.0f * sf[qh][nb][0] - mmax[qh]);
                float p1 = __expf(5.0f * sf[qh][nb][1] - mmax[qh]);
                float p2 = __expf(5.0f * sf[qh][nb][2] - mmax[qh]);
                float p3 = __expf(5.0f * sf[qh][nb][3] - mmax[qh]);
                rs += (p0 + p1) + (p2 + p3);
                uint32_t u01 = (uint32_t)f2bf(p0) | ((uint32_t)f2bf(p1) << 16);
                uint32_t u23 = (uint32_t)f2bf(p2) | ((uint32_t)f2bf(p3) << 16);
                *reinterpret_cast<uint32_t*>(ptile + (qh * 16 + r) * 144 + (nb * 16 + g * 4) * 2) = u01;
                *reinterpret_cast<uint32_t*>(ptile + (qh * 16 + r) * 144 + (nb * 16 + g * 4) * 2 + 4) = u23;
            }
            rs += __shfl_xor(rs, 16);
            rs += __shfl_xor(rs, 32);
            lsum[qh] += rs;
        }

        // ---- out^T += Vt . P^T : 32 vf reads -> 64 MFMAs
        bf16x8 pb[2][2];
        #pragma unroll
        for (int qh = 0; qh < 2; qh++)
            #pragma unroll
            for (int ch = 0; ch < 2; ch++)
                pb[qh][ch] = *reinterpret_cast<const bf16x8*>(
                    ptile + (qh * 16 + r) * 144 + ch * 64 + g * 16);
        #pragma unroll
        for (int cf = 0; cf < 16; cf++) {
            #pragma unroll
            for (int ch = 0; ch < 2; ch++) {
                int c = cf * 16 + r;
                int slot = (ch * 4 + g) ^ (r & 7);
                bf16x8 vf = *reinterpret_cast<const bf16x8*>(vb + c * 128 + slot * 16);
                acc[0][cf] = __builtin_amdgcn_mfma_f32_16x16x32_bf16(vf, pb[0][ch], acc[0][cf], 0, 0, 0);
                acc[1][cf] = __builtin_amdgcn_mfma_f32_16x16x32_bf16(vf, pb[1][ch], acc[1][cf], 0, 0, 0);
            }
        }

        __syncthreads();   // drains this step's stage loads + all LDS reads
    }

    // ---- epilogue: 1/lsum, LayerNorm across the 4 lanes sharing r, LeakyReLU
    #pragma unroll
    for (int qh = 0; qh < 2; qh++) {
        float inv = 1.0f / lsum[qh];
        float s = 0.0f, q2 = 0.0f;
        #pragma unroll
        for (int cf = 0; cf < 16; cf++) {
            #pragma unroll
            for (int j = 0; j < 4; j++) {
                float v = acc[qh][cf][j] * inv;
                acc[qh][cf][j] = v;
                s += v; q2 += v * v;
            }
        }
        s  += __shfl_xor(s, 16);  s  += __shfl_xor(s, 32);
        q2 += __shfl_xor(q2, 16); q2 += __shfl_xor(q2, 32);
        float mu = s * (1.0f / 256.0f);
        float var = q2 * (1.0f / 256.0f) - mu * mu;
        float rstd = rsqrtf(var + 1e-5f);
        size_t rowoff = (size_t)(q0 + qh * 16 + r) * 256;
        #pragma unroll
        for (int cf = 0; cf < 16; cf++) {
            float4 gg = *reinterpret_cast<const float4*>(gam + cf * 16 + g * 4);
            float4 bb = *reinterpret_cast<const float4*>(bet + cf * 16 + g * 4);
            float4 o;
            o.x = (acc[qh][cf][0] - mu) * rstd * gg.x + bb.x;
            o.y = (acc[qh][cf][1] - mu) * rstd * gg.y + bb.y;
            o.z = (acc[qh][cf][2] - mu) * rstd * gg.z + bb.z;
            o.w = (acc[qh][cf][3] - mu) * rstd * gg.w + bb.w;
            o.x = o.x >= 0.f ? o.x : 0.01f * o.x;
            o.y = o.y >= 0.f ? o.y : 0.01f * o.y;
            o.z = o.z >= 0.f ? o.z : 0.01f * o.z;
            o.w = o.w >= 0.f ? o.w : 0.01f * o.w;
            *reinterpret_cast<float4*>(out + rowoff + cf * 16 + g * 4) = o;
        }
    }
}

// ---------------------------------------------------------------- launcher
extern "C" void kernel_launch(void* const* d_in, const int* in_sizes, int n_in,
                              void* d_out, int out_size, void* d_ws, size_t ws_size,
                              hipStream_t stream) {
    const float* local_feat = (const float*)d_in[0];
    const float* adj_w    = (const float*)d_in[3];
    const float* affine_w = (const float*)d_in[4];
    const float* affine_b = (const float*)d_in[5];
    const float* ln_g     = (const float*)d_in[6];
    const float* ln_b     = (const float*)d_in[7];
    float* out = (float*)d_out;

    char* ws = (char*)d_ws;
    unsigned short* nf    = (unsigned short*)(ws);                 // 16 MiB
    unsigned short* q     = (unsigned short*)(ws + 16777216);      // 16 MiB
    unsigned short* vt    = (unsigned short*)(ws + 33554432);      // 16 MiB
    float*          norms = (float*)         (ws + 50331648);      // 128 KiB
    unsigned short* adjT  = (unsigned short*)(ws + 50462720);      // 128 KiB
    unsigned short* affw  = (unsigned short*)(ws + 50593792);      // 128 KiB

    prep_weights<<<256, 256, 0, stream>>>(adj_w, affine_w, adjT, affw);
    l2norm_kernel<<<BM_ / 4, 256, 0, stream>>>(local_feat, nf, norms);
    gemm_kernel<<<BM_ / 128, 512, 0, stream>>>(nf, adjT, nullptr, nullptr, q, nullptr, 0);
    gemm_kernel<<<BM_ / 128, 512, 0, stream>>>(nf, affw, norms, affine_b, nullptr, vt, 1);
    flash_kernel<<<256, 256, 0, stream>>>(q, nf, vt, ln_g, ln_b, out);
}

// Round 3
// 167.642 us; speedup vs baseline: 1.5867x; 1.1074x over previous
//
#include <hip/hip_runtime.h>
#include <hip/hip_bf16.h>
#include <stdint.h>

// Shapes (fixed by the problem)
#define B_  16
#define M_  2048            // T*N
#define C_  256
#define BM_ 32768           // B_*M_

typedef __bf16 bf16x8 __attribute__((ext_vector_type(8)));
typedef __bf16 bf16x2 __attribute__((ext_vector_type(2)));
typedef float  f32x4  __attribute__((ext_vector_type(4)));
typedef float  f32x16 __attribute__((ext_vector_type(16)));
typedef unsigned int uint2v __attribute__((ext_vector_type(2)));

__device__ __forceinline__ unsigned short f2bf(float f) {
    uint32_t u = __builtin_bit_cast(uint32_t, f);
    u += 0x7fffu + ((u >> 16) & 1u);          // RNE
    return (unsigned short)(u >> 16);
}

__device__ __forceinline__ uint32_t pkbf(float a, float b) {
    bf16x2 t; t[0] = (__bf16)a; t[1] = (__bf16)b;   // compiler -> v_cvt_pk_bf16_f32
    return __builtin_bit_cast(uint32_t, t);
}

// async global->LDS, 16B/lane; LDS dest = wave-uniform base, HW adds lane*16
__device__ __forceinline__ void gload16(const void* g, void* l) {
    __builtin_amdgcn_global_load_lds(
        (const __attribute__((address_space(1))) void*)g,
        (__attribute__((address_space(3))) void*)l, 16, 0, 0);
}

// ---------------------------------------------------------------- kernel 1
// adjT5 = 5*log2(e) * adj^T (logits move to exp2 domain); affwB = bf16(affine_w)
__global__ void prep_weights(const float* __restrict__ adj,
                             const float* __restrict__ affw,
                             unsigned short* __restrict__ adjT5,
                             unsigned short* __restrict__ affwB) {
    int idx = blockIdx.x * 256 + threadIdx.x;   // 0..65535
    int d = idx >> 8, c = idx & 255;
    adjT5[d * 256 + c] = f2bf(7.2134752f * adj[c * 256 + d]);
    affwB[idx] = f2bf(affw[idx]);
}

// ---------------------------------------------------------------- kernel 2
__global__ void l2norm_kernel(const float* __restrict__ x,
                              unsigned short* __restrict__ nf,
                              float* __restrict__ norms) {
    int w = threadIdx.x >> 6, lane = threadIdx.x & 63;
    int row = blockIdx.x * 4 + w;
    const float4 v = *reinterpret_cast<const float4*>(x + (size_t)row * 256 + lane * 4);
    float ss = v.x * v.x + v.y * v.y + v.z * v.z + v.w * v.w;
    #pragma unroll
    for (int m = 1; m < 64; m <<= 1) ss += __shfl_xor(ss, m);
    float nrm = sqrtf(ss);
    float s = 1.0f / fmaxf(nrm, 1e-12f);
    ushort4 o;
    o.x = f2bf(v.x * s); o.y = f2bf(v.y * s); o.z = f2bf(v.z * s); o.w = f2bf(v.w * s);
    *reinterpret_cast<ushort4*>(nf + (size_t)row * 256 + lane * 4) = o;
    if (lane == 0) norms[row] = nrm;
}

// ---------------------------------------------------------------- kernel 3
// One pass over nf producing BOTH Q = nf@adjT5 (row-major) and
// Vt = norms*(nf@affw)+bias (transposed [256][BM]).
__global__ __launch_bounds__(512, 2)
void dual_gemm(const unsigned short* __restrict__ A,
               const unsigned short* __restrict__ B1,
               const unsigned short* __restrict__ B2,
               const float* __restrict__ norms,
               const float* __restrict__ bias,
               unsigned short* __restrict__ outQ,
               unsigned short* __restrict__ outT) {
    __shared__ unsigned short bb1[256 * 56];
    __shared__ unsigned short bb2[256 * 56];
    int tid = threadIdx.x;
    int w = tid >> 6, lane = tid & 63, g = lane >> 4, r = lane & 15;
    int m0 = blockIdx.x * 128;

    const f32x4 z = {0.f, 0.f, 0.f, 0.f};
    f32x4 accq[16], accv[16];
    #pragma unroll
    for (int i = 0; i < 16; i++) { accq[i] = z; accv[i] = z; }

    for (int dc = 0; dc < 8; dc++) {
        __syncthreads();
        #pragma unroll
        for (int it = 0; it < 2; it++) {
            int n = (w * 2 + it) * 16 + (lane >> 2);
            int t = lane & 3;
            *reinterpret_cast<uint4*>(&bb1[n * 56 + t * 8]) =
                *reinterpret_cast<const uint4*>(B1 + (size_t)n * 256 + dc * 32 + t * 8);
            *reinterpret_cast<uint4*>(&bb2[n * 56 + t * 8]) =
                *reinterpret_cast<const uint4*>(B2 + (size_t)n * 256 + dc * 32 + t * 8);
        }
        __syncthreads();
        bf16x8 af = *reinterpret_cast<const bf16x8*>(
            A + (size_t)(m0 + w * 16 + r) * 256 + dc * 32 + g * 8);
        #pragma unroll
        for (int nf16 = 0; nf16 < 16; nf16++) {
            bf16x8 b1f = *reinterpret_cast<const bf16x8*>(&bb1[(nf16 * 16 + r) * 56 + g * 8]);
            accq[nf16] = __builtin_amdgcn_mfma_f32_16x16x32_bf16(af, b1f, accq[nf16], 0, 0, 0);
            bf16x8 b2f = *reinterpret_cast<const bf16x8*>(&bb2[(nf16 * 16 + r) * 56 + g * 8]);
            accv[nf16] = __builtin_amdgcn_mfma_f32_16x16x32_bf16(af, b2f, accv[nf16], 0, 0, 0);
        }
    }
    // Q epilogue: row-major
    #pragma unroll
    for (int nf16 = 0; nf16 < 16; nf16++) {
        int n = nf16 * 16 + r;
        #pragma unroll
        for (int j = 0; j < 4; j++) {
            int m = m0 + w * 16 + g * 4 + j;
            outQ[(size_t)m * 256 + n] = f2bf(accq[nf16][j]);
        }
    }
    // V epilogue: transposed, * norms + bias
    float4 nr = *reinterpret_cast<const float4*>(norms + m0 + w * 16 + g * 4);
    #pragma unroll
    for (int nf16 = 0; nf16 < 16; nf16++) {
        int n = nf16 * 16 + r;
        float bv = bias[n];
        ushort4 o;
        o.x = f2bf(accv[nf16][0] * nr.x + bv);
        o.y = f2bf(accv[nf16][1] * nr.y + bv);
        o.z = f2bf(accv[nf16][2] * nr.z + bv);
        o.w = f2bf(accv[nf16][3] * nr.w + bv);
        *reinterpret_cast<ushort4*>(outT + (size_t)n * BM_ + m0 + w * 16 + g * 4) = o;
    }
}

// ---------------------------------------------------------------- kernel 4
// Flash v3: 512 thr = 8 waves = 2 kv-groups x 4 waves; each wave 32 q-rows
// via 32x32x16 MFMA. K/V per group double-buffered via global_load_lds
// (inverse-swizzled global source, linear LDS, swizzled reads). P stays in
// registers (cvt_pk + permlane32_swap). Defer-max softmax in exp2 domain.
// Groups merge partials through LDS; group 0 does fused LN+LeakyReLU.
// LDS: group h K/V dbuf @ h*65536 + buf*32768 (K 16KB | V 16KB) = 128KB;
// merge aliases it afterwards: 4 wg * 33280B acc + 1KB (m,l) = 134144B.
__global__ __launch_bounds__(512, 2)
void flash_kernel(const unsigned short* __restrict__ Q,
                  const unsigned short* __restrict__ K,
                  const unsigned short* __restrict__ Vt,
                  const float* __restrict__ gam,
                  const float* __restrict__ bet,
                  float* __restrict__ out) {
    __shared__ __align__(16) char smem[134144];
    const int tid = threadIdx.x;
    const int w = tid >> 6, lane = tid & 63;
    const int wg = w & 3, h = w >> 2;           // q sub-block, kv group
    const int hl = lane >> 5, m = lane & 31;    // lane half, lane-in-half
    const int blk = blockIdx.x;
    const int b = (blk & 7) * 2 + (blk >> 7);   // XCD-pinned batch
    const int mblk = (blk >> 3) & 15;
    const int q0 = b * M_ + mblk * 128 + wg * 32;

    // Q fragments: B-operand [16 k][32 q] per chunk; lane holds Q[q0+m][ch*16+hl*8..+8]
    bf16x8 qf[16];
    #pragma unroll
    for (int ch = 0; ch < 16; ch++)
        qf[ch] = *reinterpret_cast<const bf16x8*>(
            Q + (size_t)(q0 + m) * 256 + ch * 16 + hl * 8);

    const f32x16 z16 = {0,0,0,0, 0,0,0,0, 0,0,0,0, 0,0,0,0};
    f32x16 acc[8];
    #pragma unroll
    for (int cb = 0; cb < 8; cb++) acc[cb] = z16;
    float mmax = 0.0f, lsum = 0.0f;             // exp2-domain, per-lane partial lsum

    const unsigned short* Kb = K + (size_t)b * M_ * 256;

    auto stage = [&](int step, int buf) {
        const int base_kv = h * 1024 + step * 32;
        char* kb = smem + h * 65536 + buf * 32768;
        char* vb = kb + 16384;
        #pragma unroll
        for (int it = 0; it < 4; it++) {        // K tile [32][256] -> 16KB
            int s = it * 256 + wg * 64 + lane;
            int n = s >> 5, t = s & 31;
            gload16(Kb + (size_t)(base_kv + n) * 256 + ((t ^ (n & 7)) * 8),
                    kb + (it * 256 + wg * 64) * 16);
        }
        #pragma unroll
        for (int it = 0; it < 4; it++) {        // V tile [256][32] -> 16KB
            int s = it * 256 + wg * 64 + lane;
            int c = s >> 2, t = s & 3;
            gload16(Vt + (size_t)c * BM_ + (size_t)b * M_ + base_kv + ((t ^ (c & 3)) * 8),
                    vb + (it * 256 + wg * 64) * 16);
        }
    };

    stage(0, 0);
    __syncthreads();

    #pragma unroll 2
    for (int step = 0; step < 32; step++) {
        const int cur = step & 1;
        if (step + 1 < 32) stage(step + 1, cur ^ 1);
        char* kb = smem + h * 65536 + cur * 32768;
        char* vb = kb + 16384;

        // ---- S^T[32 kv][32 q] = K . Q^T over 16 k-chunks
        f32x16 sf = z16;
        #pragma unroll
        for (int ch = 0; ch < 16; ch++) {
            int slot = (ch * 2 + hl) ^ (m & 7);
            bf16x8 kf = *reinterpret_cast<const bf16x8*>(kb + m * 512 + slot * 16);
            sf = __builtin_amdgcn_mfma_f32_32x32x16_bf16(kf, qf[ch], sf, 0, 0, 0);
        }

        // ---- online softmax (exp2 domain), defer-max THR=11
        float tm = sf[0];
        #pragma unroll
        for (int i = 1; i < 16; i++) tm = fmaxf(tm, sf[i]);
        tm = fmaxf(tm, __shfl_xor(tm, 32));
        if (__any(tm > mmax + 11.0f)) {
            float mn = fmaxf(mmax, tm);
            float corr = exp2f(mmax - mn);
            lsum *= corr;
            #pragma unroll
            for (int cb = 0; cb < 8; cb++) acc[cb] *= corr;
            mmax = mn;
        }
        #pragma unroll
        for (int i = 0; i < 16; i++) {
            sf[i] = exp2f(sf[i] - mmax);
            lsum += sf[i];
        }
        // pack P pairs; lane holds P[q=m][kv=(reg&3)+8*(reg>>2)+4*hl]
        uint32_t pk0 = pkbf(sf[0], sf[1]),  pk1 = pkbf(sf[2], sf[3]);
        uint32_t pk2 = pkbf(sf[4], sf[5]),  pk3 = pkbf(sf[6], sf[7]);
        uint32_t pk4 = pkbf(sf[8], sf[9]),  pk5 = pkbf(sf[10], sf[11]);
        uint32_t pk6 = pkbf(sf[12], sf[13]), pk7 = pkbf(sf[14], sf[15]);
        // permlane32_swap: res[0]={a_lo,b_lo}, res[1]={a_hi,b_hi}
        uint2v r0 = __builtin_amdgcn_permlane32_swap(pk0, pk2, false, false);
        uint2v r1 = __builtin_amdgcn_permlane32_swap(pk1, pk3, false, false);
        uint2v r2 = __builtin_amdgcn_permlane32_swap(pk4, pk6, false, false);
        uint2v r3 = __builtin_amdgcn_permlane32_swap(pk5, pk7, false, false);
        uint4 u0; u0.x = r0[0]; u0.y = r1[0]; u0.z = r0[1]; u0.w = r1[1];
        uint4 u1; u1.x = r2[0]; u1.y = r3[0]; u1.z = r2[1]; u1.w = r3[1];
        bf16x8 pf0 = __builtin_bit_cast(bf16x8, u0);   // P^T[kv 0..15][q]
        bf16x8 pf1 = __builtin_bit_cast(bf16x8, u1);   // P^T[kv 16..31][q]

        // ---- out^T[c][q] += Vt . P^T  (8 c-blocks x 2 k-chunks)
        #pragma unroll
        for (int cb = 0; cb < 8; cb++) {
            int c = cb * 32 + m;
            bf16x8 v0 = *reinterpret_cast<const bf16x8*>(
                vb + c * 64 + ((hl ^ (m & 3)) * 16));
            acc[cb] = __builtin_amdgcn_mfma_f32_32x32x16_bf16(v0, pf0, acc[cb], 0, 0, 0);
            bf16x8 v1 = *reinterpret_cast<const bf16x8*>(
                vb + c * 64 + (((2 + hl) ^ (m & 3)) * 16));
            acc[cb] = __builtin_amdgcn_mfma_f32_32x32x16_bf16(v1, pf1, acc[cb], 0, 0, 0);
        }

        __syncthreads();   // drains stage(step+1) + all LDS reads of buf cur
    }

    // ---- cross-half lsum (per q-row total for this group's kv half)
    lsum += __shfl_xor(lsum, 32);

    // ---- group merge through LDS (aliases K/V buffers; stride 260 f32)
    float* mp  = (float*)smem;
    float* mlp = (float*)(smem + 133120);
    if (h == 1) {
        #pragma unroll
        for (int cb = 0; cb < 8; cb++)
            #pragma unroll
            for (int q4 = 0; q4 < 4; q4++) {
                float4 v;
                v.x = acc[cb][q4 * 4 + 0]; v.y = acc[cb][q4 * 4 + 1];
                v.z = acc[cb][q4 * 4 + 2]; v.w = acc[cb][q4 * 4 + 3];
                *reinterpret_cast<float4*>(
                    mp + wg * 8320 + m * 260 + cb * 32 + q4 * 8 + 4 * hl) = v;
            }
        if (hl == 0) {
            float2 ml; ml.x = mmax; ml.y = lsum;
            *reinterpret_cast<float2*>(mlp + (wg * 32 + m) * 2) = ml;
        }
    }
    __syncthreads();
    if (h == 0) {
        float2 ml1 = *reinterpret_cast<const float2*>(mlp + (wg * 32 + m) * 2);
        float mn = fmaxf(mmax, ml1.x);
        float c0 = exp2f(mmax - mn), c1 = exp2f(ml1.x - mn);
        lsum = lsum * c0 + ml1.y * c1;
        #pragma unroll
        for (int cb = 0; cb < 8; cb++)
            #pragma unroll
            for (int q4 = 0; q4 < 4; q4++) {
                float4 a1 = *reinterpret_cast<const float4*>(
                    mp + wg * 8320 + m * 260 + cb * 32 + q4 * 8 + 4 * hl);
                acc[cb][q4 * 4 + 0] = acc[cb][q4 * 4 + 0] * c0 + a1.x * c1;
                acc[cb][q4 * 4 + 1] = acc[cb][q4 * 4 + 1] * c0 + a1.y * c1;
                acc[cb][q4 * 4 + 2] = acc[cb][q4 * 4 + 2] * c0 + a1.z * c1;
                acc[cb][q4 * 4 + 3] = acc[cb][q4 * 4 + 3] * c0 + a1.w * c1;
            }
        // ---- fused LayerNorm + LeakyReLU; lane holds 128 of 256 channels
        float inv = 1.0f / lsum;
        float s = 0.0f, ssq = 0.0f;
        #pragma unroll
        for (int cb = 0; cb < 8; cb++)
            #pragma unroll
            for (int i = 0; i < 16; i++) {
                float v = acc[cb][i] * inv;
                acc[cb][i] = v;
                s += v; ssq += v * v;
            }
        s   += __shfl_xor(s, 32);
        ssq += __shfl_xor(ssq, 32);
        float mu = s * (1.0f / 256.0f);
        float var = ssq * (1.0f / 256.0f) - mu * mu;
        float rstd = rsqrtf(var + 1e-5f);
        size_t rowoff = (size_t)(q0 + m) * 256;
        #pragma unroll
        for (int cb = 0; cb < 8; cb++)
            #pragma unroll
            for (int q4 = 0; q4 < 4; q4++) {
                int c0i = cb * 32 + q4 * 8 + 4 * hl;
                float4 gg = *reinterpret_cast<const float4*>(gam + c0i);
                float4 bb = *reinterpret_cast<const float4*>(bet + c0i);
                float4 o;
                o.x = (acc[cb][q4 * 4 + 0] - mu) * rstd * gg.x + bb.x;
                o.y = (acc[cb][q4 * 4 + 1] - mu) * rstd * gg.y + bb.y;
                o.z = (acc[cb][q4 * 4 + 2] - mu) * rstd * gg.z + bb.z;
                o.w = (acc[cb][q4 * 4 + 3] - mu) * rstd * gg.w + bb.w;
                o.x = o.x >= 0.f ? o.x : 0.01f * o.x;
                o.y = o.y >= 0.f ? o.y : 0.01f * o.y;
                o.z = o.z >= 0.f ? o.z : 0.01f * o.z;
                o.w = o.w >= 0.f ? o.w : 0.01f * o.w;
                *reinterpret_cast<float4*>(out + rowoff + c0i) = o;
            }
    }
}

// ---------------------------------------------------------------- launcher
extern "C" void kernel_launch(void* const* d_in, const int* in_sizes, int n_in,
                              void* d_out, int out_size, void* d_ws, size_t ws_size,
                              hipStream_t stream) {
    const float* local_feat = (const float*)d_in[0];
    const float* adj_w    = (const float*)d_in[3];
    const float* affine_w = (const float*)d_in[4];
    const float* affine_b = (const float*)d_in[5];
    const float* ln_g     = (const float*)d_in[6];
    const float* ln_b     = (const float*)d_in[7];
    float* out = (float*)d_out;

    char* ws = (char*)d_ws;
    unsigned short* nf    = (unsigned short*)(ws);                 // 16 MiB
    unsigned short* q     = (unsigned short*)(ws + 16777216);      // 16 MiB
    unsigned short* vt    = (unsigned short*)(ws + 33554432);      // 16 MiB
    float*          norms = (float*)         (ws + 50331648);      // 128 KiB
    unsigned short* adjT5 = (unsigned short*)(ws + 50462720);      // 128 KiB
    unsigned short* affw  = (unsigned short*)(ws + 50593792);      // 128 KiB

    prep_weights<<<256, 256, 0, stream>>>(adj_w, affine_w, adjT5, affw);
    l2norm_kernel<<<BM_ / 4, 256, 0, stream>>>(local_feat, nf, norms);
    dual_gemm<<<BM_ / 128, 512, 0, stream>>>(nf, adjT5, affw, norms, affine_b, q, vt);
    flash_kernel<<<256, 512, 0, stream>>>(q, nf, vt, ln_g, ln_b, out);
}

// Round 5
// 161.223 us; speedup vs baseline: 1.6498x; 1.0398x over previous
//
#include <hip/hip_runtime.h>
#include <hip/hip_bf16.h>
#include <stdint.h>

// Shapes (fixed by the problem)
#define B_  16
#define M_  2048            // T*N
#define C_  256
#define BM_ 32768           // B_*M_

typedef __bf16 bf16x8 __attribute__((ext_vector_type(8)));
typedef __bf16 bf16x2 __attribute__((ext_vector_type(2)));
typedef float  f32x4  __attribute__((ext_vector_type(4)));
typedef float  f32x16 __attribute__((ext_vector_type(16)));
typedef unsigned int uint2v __attribute__((ext_vector_type(2)));

__device__ __forceinline__ unsigned short f2bf(float f) {
    uint32_t u = __builtin_bit_cast(uint32_t, f);
    u += 0x7fffu + ((u >> 16) & 1u);          // RNE
    return (unsigned short)(u >> 16);
}

__device__ __forceinline__ uint32_t pkbf(float a, float b) {
    bf16x2 t; t[0] = (__bf16)a; t[1] = (__bf16)b;   // compiler -> v_cvt_pk_bf16_f32
    return __builtin_bit_cast(uint32_t, t);
}

// async global->LDS, 16B/lane; LDS dest = wave-uniform base, HW adds lane*16
__device__ __forceinline__ void gload16(const void* g, void* l) {
    __builtin_amdgcn_global_load_lds(
        (const __attribute__((address_space(1))) void*)g,
        (__attribute__((address_space(3))) void*)l, 16, 0, 0);
}

// Explicit LDS-DMA publish: drain vmcnt BEFORE the barrier (do not rely on
// __syncthreads to drain global_load_lds), and fence the scheduler so
// nothing crosses in either direction (guide rule #18 / T3 recipe).
__device__ __forceinline__ void publish_barrier() {
    asm volatile("s_waitcnt vmcnt(0)" ::: "memory");
    __builtin_amdgcn_sched_barrier(0);
    __syncthreads();
    __builtin_amdgcn_sched_barrier(0);
}

// ---------------------------------------------------------------- kernel 1
// adjT5 = 5*log2(e) * adj^T (logits in exp2 domain); affwB = bf16(affine_w)
__global__ void prep_weights(const float* __restrict__ adj,
                             const float* __restrict__ affw,
                             unsigned short* __restrict__ adjT5,
                             unsigned short* __restrict__ affwB) {
    int idx = blockIdx.x * 256 + threadIdx.x;   // 0..65535
    int d = idx >> 8, c = idx & 255;
    adjT5[d * 256 + c] = f2bf(7.2134752f * adj[c * 256 + d]);
    affwB[idx] = f2bf(affw[idx]);
}

// ---------------------------------------------------------------- kernel 2
__global__ void l2norm_kernel(const float* __restrict__ x,
                              unsigned short* __restrict__ nf,
                              float* __restrict__ norms) {
    int w = threadIdx.x >> 6, lane = threadIdx.x & 63;
    int row = blockIdx.x * 4 + w;
    const float4 v = *reinterpret_cast<const float4*>(x + (size_t)row * 256 + lane * 4);
    float ss = v.x * v.x + v.y * v.y + v.z * v.z + v.w * v.w;
    #pragma unroll
    for (int m = 1; m < 64; m <<= 1) ss += __shfl_xor(ss, m);
    float nrm = sqrtf(ss);
    float s = 1.0f / fmaxf(nrm, 1e-12f);
    ushort4 o;
    o.x = f2bf(v.x * s); o.y = f2bf(v.y * s); o.z = f2bf(v.z * s); o.w = f2bf(v.w * s);
    *reinterpret_cast<ushort4*>(nf + (size_t)row * 256 + lane * 4) = o;
    if (lane == 0) norms[row] = nrm;
}

// ---------------------------------------------------------------- kernel 3
// One pass over nf producing BOTH Q = nf@adjT5 (row-major) and
// Vt = norms*(nf@affw)+bias (transposed [256][BM]).
__global__ __launch_bounds__(512, 2)
void dual_gemm(const unsigned short* __restrict__ A,
               const unsigned short* __restrict__ B1,
               const unsigned short* __restrict__ B2,
               const float* __restrict__ norms,
               const float* __restrict__ bias,
               unsigned short* __restrict__ outQ,
               unsigned short* __restrict__ outT) {
    __shared__ unsigned short bb1[256 * 56];
    __shared__ unsigned short bb2[256 * 56];
    int tid = threadIdx.x;
    int w = tid >> 6, lane = tid & 63, g = lane >> 4, r = lane & 15;
    int m0 = blockIdx.x * 128;

    const f32x4 z = {0.f, 0.f, 0.f, 0.f};
    f32x4 accq[16], accv[16];
    #pragma unroll
    for (int i = 0; i < 16; i++) { accq[i] = z; accv[i] = z; }

    for (int dc = 0; dc < 8; dc++) {
        __syncthreads();
        #pragma unroll
        for (int it = 0; it < 2; it++) {
            int n = (w * 2 + it) * 16 + (lane >> 2);
            int t = lane & 3;
            *reinterpret_cast<uint4*>(&bb1[n * 56 + t * 8]) =
                *reinterpret_cast<const uint4*>(B1 + (size_t)n * 256 + dc * 32 + t * 8);
            *reinterpret_cast<uint4*>(&bb2[n * 56 + t * 8]) =
                *reinterpret_cast<const uint4*>(B2 + (size_t)n * 256 + dc * 32 + t * 8);
        }
        __syncthreads();
        bf16x8 af = *reinterpret_cast<const bf16x8*>(
            A + (size_t)(m0 + w * 16 + r) * 256 + dc * 32 + g * 8);
        #pragma unroll
        for (int nf16 = 0; nf16 < 16; nf16++) {
            bf16x8 b1f = *reinterpret_cast<const bf16x8*>(&bb1[(nf16 * 16 + r) * 56 + g * 8]);
            accq[nf16] = __builtin_amdgcn_mfma_f32_16x16x32_bf16(af, b1f, accq[nf16], 0, 0, 0);
            bf16x8 b2f = *reinterpret_cast<const bf16x8*>(&bb2[(nf16 * 16 + r) * 56 + g * 8]);
            accv[nf16] = __builtin_amdgcn_mfma_f32_16x16x32_bf16(af, b2f, accv[nf16], 0, 0, 0);
        }
    }
    // Q epilogue: row-major
    #pragma unroll
    for (int nf16 = 0; nf16 < 16; nf16++) {
        int n = nf16 * 16 + r;
        #pragma unroll
        for (int j = 0; j < 4; j++) {
            int m = m0 + w * 16 + g * 4 + j;
            outQ[(size_t)m * 256 + n] = f2bf(accq[nf16][j]);
        }
    }
    // V epilogue: transposed, * norms + bias
    float4 nr = *reinterpret_cast<const float4*>(norms + m0 + w * 16 + g * 4);
    #pragma unroll
    for (int nf16 = 0; nf16 < 16; nf16++) {
        int n = nf16 * 16 + r;
        float bv = bias[n];
        ushort4 o;
        o.x = f2bf(accv[nf16][0] * nr.x + bv);
        o.y = f2bf(accv[nf16][1] * nr.y + bv);
        o.z = f2bf(accv[nf16][2] * nr.z + bv);
        o.w = f2bf(accv[nf16][3] * nr.w + bv);
        *reinterpret_cast<ushort4*>(outT + (size_t)n * BM_ + m0 + w * 16 + g * 4) = o;
    }
}

// ---------------------------------------------------------------- kernel 4
// Flash v5 = v4 pipeline + EXPLICIT vmcnt publish barriers (race fix).
// 512 thr = 2 kv-groups x 4 waves; each wave 32 q via 32x32x16.
// K double-buffered, V TRIPLE-buffered (global_load_lds, linear dest).
// One barrier per step right after QK; stage(step+2) issued post-barrier;
// softmax+PV post-barrier (V[cur] not overwritten until step+3).
// V tile layout: slot s = (c>>3)*32 + j*8 + (c&7)  (conflict-free reads).
// LDS per group (80KB): K0@0 K1@16K V0@32K V1@48K V2@64K; groups at 0/80K.
// Merge epilogue aliases smem base (134144B <= 163840).
__global__ __launch_bounds__(512, 1)
void flash_kernel(const unsigned short* __restrict__ Q,
                  const unsigned short* __restrict__ K,
                  const unsigned short* __restrict__ Vt,
                  const float* __restrict__ gam,
                  const float* __restrict__ bet,
                  float* __restrict__ out) {
    __shared__ __align__(16) char smem[163840];
    const int tid = threadIdx.x;
    const int w = tid >> 6, lane = tid & 63;
    const int wg = w & 3, h = w >> 2;           // q sub-block, kv group
    const int hl = lane >> 5, m = lane & 31;    // lane half, lane-in-half
    const int blk = blockIdx.x;
    const int b = (blk & 7) * 2 + (blk >> 7);   // XCD-pinned batch
    const int mblk = (blk >> 3) & 15;
    const int q0 = b * M_ + mblk * 128 + wg * 32;

    char* gbase = smem + h * 81920;

    // Q fragments: B-operand; lane holds Q[q0+m][ch*16 + hl*8 ..+8]
    bf16x8 qf[16];
    #pragma unroll
    for (int ch = 0; ch < 16; ch++)
        qf[ch] = *reinterpret_cast<const bf16x8*>(
            Q + (size_t)(q0 + m) * 256 + ch * 16 + hl * 8);

    const f32x16 z16 = {0,0,0,0, 0,0,0,0, 0,0,0,0, 0,0,0,0};
    f32x16 acc[8];
    #pragma unroll
    for (int cb = 0; cb < 8; cb++) acc[cb] = z16;
    float mmax = 0.0f, lsum = 0.0f;             // exp2 domain

    const unsigned short* Kb = K + (size_t)b * M_ * 256;

    auto stageK = [&](int step, int ksel) {
        const int base_kv = h * 1024 + step * 32;
        char* kb = gbase + ksel * 16384;
        #pragma unroll
        for (int it = 0; it < 4; it++) {
            int s = it * 256 + wg * 64 + lane;
            int n = s >> 5, t = s & 31;
            gload16(Kb + (size_t)(base_kv + n) * 256 + ((t ^ (n & 7)) * 8),
                    kb + (it * 256 + wg * 64) * 16);
        }
    };
    auto stageV = [&](int step, int vsel) {
        const int base_kv = h * 1024 + step * 32;
        char* vb = gbase + 32768 + vsel * 16384;
        #pragma unroll
        for (int it = 0; it < 4; it++) {
            int s = it * 256 + wg * 64 + lane;
            int c = ((s >> 5) << 3) + (s & 7);  // slot -> (c, j) decode
            int j = (s >> 3) & 3;
            gload16(Vt + (size_t)c * BM_ + (size_t)b * M_ + base_kv + j * 8,
                    vb + (it * 256 + wg * 64) * 16);
        }
    };

    stageK(0, 0); stageV(0, 0);
    publish_barrier();                          // K0/V0 visible to all waves
    stageK(1, 1); stageV(1, 1);

    int vcur = 0;
    for (int step = 0; step < 32; step++) {
        char* kb = gbase + (step & 1) * 16384;
        char* vb = gbase + 32768 + vcur * 16384;

        // ---- S^T[32 kv][32 q] = K . Q^T  (all K reads pre-barrier)
        f32x16 sf = z16;
        __builtin_amdgcn_s_setprio(1);
        #pragma unroll
        for (int ch = 0; ch < 16; ch++) {
            int slot = (ch * 2 + hl) ^ (m & 7);
            bf16x8 kf = *reinterpret_cast<const bf16x8*>(kb + m * 512 + slot * 16);
            sf = __builtin_amdgcn_mfma_f32_32x32x16_bf16(kf, qf[ch], sf, 0, 0, 0);
        }
        __builtin_amdgcn_s_setprio(0);

        // publishes stage(step+1); K[cur] fully consumed by all waves
        publish_barrier();

        if (step + 2 < 32) {      // overwrite consumed buffers
            int vst = vcur + 2; if (vst >= 3) vst -= 3;
            stageK(step + 2, step & 1);
            stageV(step + 2, vst);
        }

        // ---- online softmax (exp2 domain), defer-max THR=11
        float tm = sf[0];
        #pragma unroll
        for (int i = 1; i < 16; i++) tm = fmaxf(tm, sf[i]);
        tm = fmaxf(tm, __shfl_xor(tm, 32));
        if (__any(tm > mmax + 11.0f)) {
            float mn = fmaxf(mmax, tm);
            float corr = exp2f(mmax - mn);
            lsum *= corr;
            #pragma unroll
            for (int cb = 0; cb < 8; cb++) acc[cb] *= corr;
            mmax = mn;
        }
        #pragma unroll
        for (int i = 0; i < 16; i++) {
            sf[i] = exp2f(sf[i] - mmax);
            lsum += sf[i];
        }
        // pack P; lane holds P[q=m][kv=(reg&3)+8*(reg>>2)+4*hl]
        uint32_t pk0 = pkbf(sf[0], sf[1]),   pk1 = pkbf(sf[2], sf[3]);
        uint32_t pk2 = pkbf(sf[4], sf[5]),   pk3 = pkbf(sf[6], sf[7]);
        uint32_t pk4 = pkbf(sf[8], sf[9]),   pk5 = pkbf(sf[10], sf[11]);
        uint32_t pk6 = pkbf(sf[12], sf[13]), pk7 = pkbf(sf[14], sf[15]);
        uint2v r0 = __builtin_amdgcn_permlane32_swap(pk0, pk2, false, false);
        uint2v r1 = __builtin_amdgcn_permlane32_swap(pk1, pk3, false, false);
        uint2v r2 = __builtin_amdgcn_permlane32_swap(pk4, pk6, false, false);
        uint2v r3 = __builtin_amdgcn_permlane32_swap(pk5, pk7, false, false);
        uint4 u0; u0.x = r0[0]; u0.y = r1[0]; u0.z = r0[1]; u0.w = r1[1];
        uint4 u1; u1.x = r2[0]; u1.y = r3[0]; u1.z = r2[1]; u1.w = r3[1];
        bf16x8 pf0 = __builtin_bit_cast(bf16x8, u0);   // P^T[kv 0..15][q]
        bf16x8 pf1 = __builtin_bit_cast(bf16x8, u1);   // P^T[kv 16..31][q]

        // ---- out^T[c][q] += Vt . P^T  (V[cur] safe: overwritten at step+3)
        __builtin_amdgcn_s_setprio(1);
        #pragma unroll
        for (int cb = 0; cb < 8; cb++) {
            int rowb = (cb * 4 + (m >> 3)) * 512 + (m & 7) * 16;
            bf16x8 v0 = *reinterpret_cast<const bf16x8*>(vb + rowb + hl * 128);
            acc[cb] = __builtin_amdgcn_mfma_f32_32x32x16_bf16(v0, pf0, acc[cb], 0, 0, 0);
            bf16x8 v1 = *reinterpret_cast<const bf16x8*>(vb + rowb + (2 + hl) * 128);
            acc[cb] = __builtin_amdgcn_mfma_f32_32x32x16_bf16(v1, pf1, acc[cb], 0, 0, 0);
        }
        __builtin_amdgcn_s_setprio(0);

        vcur++; if (vcur >= 3) vcur -= 3;
    }

    publish_barrier();                          // all K/V traffic done; alias LDS

    // ---- cross-half lsum
    lsum += __shfl_xor(lsum, 32);

    // ---- group merge through LDS
    float* mp  = (float*)smem;
    float* mlp = (float*)(smem + 133120);
    if (h == 1) {
        #pragma unroll
        for (int cb = 0; cb < 8; cb++)
            #pragma unroll
            for (int q4 = 0; q4 < 4; q4++) {
                float4 v;
                v.x = acc[cb][q4 * 4 + 0]; v.y = acc[cb][q4 * 4 + 1];
                v.z = acc[cb][q4 * 4 + 2]; v.w = acc[cb][q4 * 4 + 3];
                *reinterpret_cast<float4*>(
                    mp + wg * 8320 + m * 260 + cb * 32 + q4 * 8 + 4 * hl) = v;
            }
        if (hl == 0) {
            float2 ml; ml.x = mmax; ml.y = lsum;
            *reinterpret_cast<float2*>(mlp + (wg * 32 + m) * 2) = ml;
        }
    }
    __syncthreads();
    if (h == 0) {
        float2 ml1 = *reinterpret_cast<const float2*>(mlp + (wg * 32 + m) * 2);
        float mn = fmaxf(mmax, ml1.x);
        float c0 = exp2f(mmax - mn), c1 = exp2f(ml1.x - mn);
        lsum = lsum * c0 + ml1.y * c1;
        #pragma unroll
        for (int cb = 0; cb < 8; cb++)
            #pragma unroll
            for (int q4 = 0; q4 < 4; q4++) {
                float4 a1 = *reinterpret_cast<const float4*>(
                    mp + wg * 8320 + m * 260 + cb * 32 + q4 * 8 + 4 * hl);
                acc[cb][q4 * 4 + 0] = acc[cb][q4 * 4 + 0] * c0 + a1.x * c1;
                acc[cb][q4 * 4 + 1] = acc[cb][q4 * 4 + 1] * c0 + a1.y * c1;
                acc[cb][q4 * 4 + 2] = acc[cb][q4 * 4 + 2] * c0 + a1.z * c1;
                acc[cb][q4 * 4 + 3] = acc[cb][q4 * 4 + 3] * c0 + a1.w * c1;
            }
        // ---- fused LayerNorm + LeakyReLU; lane holds 128 of 256 channels
        float inv = 1.0f / lsum;
        float s = 0.0f, ssq = 0.0f;
        #pragma unroll
        for (int cb = 0; cb < 8; cb++)
            #pragma unroll
            for (int i = 0; i < 16; i++) {
                float v = acc[cb][i] * inv;
                acc[cb][i] = v;
                s += v; ssq += v * v;
            }
        s   += __shfl_xor(s, 32);
        ssq += __shfl_xor(ssq, 32);
        float mu = s * (1.0f / 256.0f);
        float var = ssq * (1.0f / 256.0f) - mu * mu;
        float rstd = rsqrtf(var + 1e-5f);
        size_t rowoff = (size_t)(q0 + m) * 256;
        #pragma unroll
        for (int cb = 0; cb < 8; cb++)
            #pragma unroll
            for (int q4 = 0; q4 < 4; q4++) {
                int c0i = cb * 32 + q4 * 8 + 4 * hl;
                float4 gg = *reinterpret_cast<const float4*>(gam + c0i);
                float4 bb = *reinterpret_cast<const float4*>(bet + c0i);
                float4 o;
                o.x = (acc[cb][q4 * 4 + 0] - mu) * rstd * gg.x + bb.x;
                o.y = (acc[cb][q4 * 4 + 1] - mu) * rstd * gg.y + bb.y;
                o.z = (acc[cb][q4 * 4 + 2] - mu) * rstd * gg.z + bb.z;
                o.w = (acc[cb][q4 * 4 + 3] - mu) * rstd * gg.w + bb.w;
                o.x = o.x >= 0.f ? o.x : 0.01f * o.x;
                o.y = o.y >= 0.f ? o.y : 0.01f * o.y;
                o.z = o.z >= 0.f ? o.z : 0.01f * o.z;
                o.w = o.w >= 0.f ? o.w : 0.01f * o.w;
                *reinterpret_cast<float4*>(out + rowoff + c0i) = o;
            }
    }
}

// ---------------------------------------------------------------- launcher
extern "C" void kernel_launch(void* const* d_in, const int* in_sizes, int n_in,
                              void* d_out, int out_size, void* d_ws, size_t ws_size,
                              hipStream_t stream) {
    const float* local_feat = (const float*)d_in[0];
    const float* adj_w    = (const float*)d_in[3];
    const float* affine_w = (const float*)d_in[4];
    const float* affine_b = (const float*)d_in[5];
    const float* ln_g     = (const float*)d_in[6];
    const float* ln_b     = (const float*)d_in[7];
    float* out = (float*)d_out;

    char* ws = (char*)d_ws;
    unsigned short* nf    = (unsigned short*)(ws);                 // 16 MiB
    unsigned short* q     = (unsigned short*)(ws + 16777216);      // 16 MiB
    unsigned short* vt    = (unsigned short*)(ws + 33554432);      // 16 MiB
    float*          norms = (float*)         (ws + 50331648);      // 128 KiB
    unsigned short* adjT5 = (unsigned short*)(ws + 50462720);      // 128 KiB
    unsigned short* affw  = (unsigned short*)(ws + 50593792);      // 128 KiB

    prep_weights<<<256, 256, 0, stream>>>(adj_w, affine_w, adjT5, affw);
    l2norm_kernel<<<BM_ / 4, 256, 0, stream>>>(local_feat, nf, norms);
    dual_gemm<<<BM_ / 128, 512, 0, stream>>>(nf, adjT5, affw, norms, affine_b, q, vt);
    flash_kernel<<<256, 512, 0, stream>>>(q, nf, vt, ln_g, ln_b, out);
}